// Round 4
// baseline (451.684 us; speedup 1.0000x reference)
//
#include <hip/hip_runtime.h>
#include <math.h>

#define NN   87
#define NN2  (NN * NN)        // 7569
#define SP   104              // sD / W-panel row stride (bf16); 208B = 13*16B
#define PANEL (96 * SP)       // 9984 shorts per panel
#define NT   256

// ws layout (bytes)
#define WS_W    0                       // 2 panels bf16 W     : 39936 B
#define WS_E    (2 * PANEL * 2)         // last-batch E padded : 7632 f
#define WS_X    (WS_E + 7632 * 4)       // last-batch x padded : 7632 f
#define WS_LAM  (WS_X + 7632 * 4)       // last-batch evals    : 96 f
#define WS_NEED (WS_LAM + 96 * 4)       // 101376 B

typedef __attribute__((ext_vector_type(8))) short bf16x8;
typedef __attribute__((ext_vector_type(4))) short bf16x4;
typedef __attribute__((ext_vector_type(4))) float f32x4;
typedef float f32x4u __attribute__((ext_vector_type(4), aligned(4)));

__device__ __forceinline__ short f2bf(float f) {
    union { float f; unsigned u; } v; v.f = f;
    unsigned r = v.u + 0x7FFFu + ((v.u >> 16) & 1u);   // RNE
    return (short)(r >> 16);
}

// 8 consecutive floats; vector path may read <=36B past the row (masked later),
// scalar path clamps flat index (used only for the last batch without ws copies).
__device__ __forceinline__ void ld8tail(const float* __restrict__ base, int off,
                                        bool scalarTail, float v[8]) {
    if (!scalarTail) {
        f32x4u a = *(const f32x4u*)(base + off);
        f32x4u b4 = *(const f32x4u*)(base + off + 4);
        v[0] = a.x; v[1] = a.y; v[2] = a.z; v[3] = a.w;
        v[4] = b4.x; v[5] = b4.y; v[6] = b4.z; v[7] = b4.w;
    } else {
        #pragma unroll
        for (int q = 0; q < 8; ++q) {
            int id = off + q;
            v[q] = base[(id < NN2) ? id : (NN2 - 1)];
        }
    }
}

// Build W panels (bf16, zero-padded 96x104) + safe padded copies of last batch's E/x/evals.
__global__ void prep(const float* __restrict__ W, const float* __restrict__ evals,
                     const float* __restrict__ evecs, const float* __restrict__ x,
                     int B, char* __restrict__ ws)
{
    int idx = (int)blockIdx.x * NT + (int)threadIdx.x;
    short* wp = (short*)(ws + WS_W);
    float* ep = (float*)(ws + WS_E);
    float* xp = (float*)(ws + WS_X);
    float* lp = (float*)(ws + WS_LAM);

    if (idx < 2 * PANEL) {
        int p = idx / PANEL, rem = idx - p * PANEL;
        int r = rem / SP, c = rem - r * SP;
        short v = 0;
        if (r < NN && c < NN) v = f2bf(W[r * (2 * NN) + p * NN + c]);
        wp[idx] = v;
    }
    int i2 = idx - 2 * PANEL;
    if (i2 >= 0 && i2 < 7632) ep[i2] = (i2 < NN2) ? evecs[(size_t)(B - 1) * NN2 + i2] : 0.f;
    int i3 = i2 - 7632;
    if (i3 >= 0 && i3 < 7632) xp[i3] = (i3 < NN2) ? x[(size_t)(B - 1) * NN2 + i3] : 0.f;
    int i4 = i3 - 7632;
    if (i4 >= 0 && i4 < 96)   lp[i4] = (i4 < NN) ? evals[(size_t)(B - 1) * NN + i4] : 0.f;
}

// W fragment: bf16 panel from ws (WS) or fp32 W with conversion + k-pad zeroing (!WS).
template <bool WS>
__device__ __forceinline__ bf16x8 wload(const short* __restrict__ wp,
                                        const float* __restrict__ gW,
                                        int panel, int jrow, int jcl, int k0, bool tailKs)
{
    if constexpr (WS) {
        return *(const bf16x8*)&wp[panel * PANEL + jrow * SP + k0];
    } else {
        float v[8];
        if (!tailKs) {
            f32x4u a = *(const f32x4u*)(gW + jcl * (2 * NN) + panel * NN + k0);
            f32x4u b4 = *(const f32x4u*)(gW + jcl * (2 * NN) + panel * NN + k0 + 4);
            v[0] = a.x; v[1] = a.y; v[2] = a.z; v[3] = a.w;
            v[4] = b4.x; v[5] = b4.y; v[6] = b4.z; v[7] = b4.w;
        } else {
            #pragma unroll
            for (int q = 0; q < 8; ++q) {
                int k = k0 + q;
                v[q] = (k < NN) ? gW[jcl * (2 * NN) + panel * NN + k] : 0.f;
            }
        }
        bf16x8 o;
        #pragma unroll
        for (int q = 0; q < 8; ++q) o[q] = f2bf(v[q]);
        return o;
    }
}

template <bool WS>
__global__ __launch_bounds__(NT, 8)
void fused(const float* __restrict__ gx, const float* __restrict__ gevals,
           const float* __restrict__ gevecs, const float* __restrict__ dtime,
           const float* __restrict__ gW, const float* __restrict__ bias,
           const char* __restrict__ ws, int B, float* __restrict__ out)
{
    __shared__ __align__(16) short sD[PANEL];   // only LDS: the diffusion kernel tile

    const int b    = (int)blockIdx.x;
    const int tid  = (int)threadIdx.x;
    const int lane = tid & 63;
    const int wave = tid >> 6;
    const int l15  = lane & 15;
    const int lk   = lane >> 4;
    const int i0   = (wave >> 1) * 48;
    const int j0   = (wave & 1) * 48;

    const float* Eb   = gevecs + (size_t)b * NN2;
    const float* xb   = gx     + (size_t)b * NN2;
    const float* lamb = gevals + (size_t)b * NN;
    const short* wp = nullptr;
    if constexpr (WS) {
        wp = (const short*)(ws + WS_W);
        if (b == B - 1) {                     // page-safe padded copies
            Eb   = (const float*)(ws + WS_E);
            xb   = (const float*)(ws + WS_X);
            lamb = (const float*)(ws + WS_LAM);
        }
    }
    const bool tailScalar = (!WS) && (b == B - 1);

    int ia[3], ja[3];
    float tr[3];
    #pragma unroll
    for (int r = 0; r < 3; ++r) {
        int i = i0 + 16 * r + l15;
        ia[r] = (i < NN) ? i : (NN - 1);      // clamped row addr; garbage rows are discarded
        tr[r] = fmaxf(dtime[ia[r]], 1e-8f);
        int j = j0 + 16 * r + l15;
        ja[r] = (j < NN) ? j : (NN - 1);
    }

    // ---------------- GEMM1: D = (E .* exp(-t_i lam_k)) @ E^T ----------------
    // Operand order mfma(ef, af): acc1[c][r] -> reg dim = E-row j, l15 = A-row i.
    f32x4 acc1[3][3];
    #pragma unroll
    for (int c = 0; c < 3; ++c)
        #pragma unroll
        for (int r = 0; r < 3; ++r) acc1[c][r] = (f32x4){0.f, 0.f, 0.f, 0.f};

    #pragma unroll
    for (int ks = 0; ks < 3; ++ks) {
        const int k0 = ks * 32 + lk * 8;

        float l8[8];
        if (ks < 2 || !tailScalar) {
            f32x4u a  = *(const f32x4u*)(lamb + k0);
            f32x4u c4 = *(const f32x4u*)(lamb + k0 + 4);
            l8[0] = a.x; l8[1] = a.y; l8[2] = a.z; l8[3] = a.w;
            l8[4] = c4.x; l8[5] = c4.y; l8[6] = c4.z; l8[7] = c4.w;
        } else {
            #pragma unroll
            for (int q = 0; q < 8; ++q) { int k = k0 + q; l8[q] = lamb[(k < NN) ? k : (NN - 1)]; }
        }
        if (ks == 2) {
            #pragma unroll
            for (int q = 0; q < 8; ++q)
                if (lk * 8 + q >= 23) l8[q] = 3e38f;   // k >= 87 -> exp(-t*BIG) = 0 mask
        }

        bf16x8 ef[3], af[3];
        #pragma unroll
        for (int c = 0; c < 3; ++c) {
            float v[8];
            ld8tail(Eb, ja[c] * NN + k0, (ks == 2) && tailScalar, v);
            #pragma unroll
            for (int q = 0; q < 8; ++q) ef[c][q] = f2bf(v[q]);
        }
        #pragma unroll
        for (int r = 0; r < 3; ++r) {
            float v[8];
            ld8tail(Eb, ia[r] * NN + k0, (ks == 2) && tailScalar, v);
            #pragma unroll
            for (int q = 0; q < 8; ++q)
                af[r][q] = f2bf(v[q] * __expf(-tr[r] * l8[q]));
        }
        #pragma unroll
        for (int c = 0; c < 3; ++c)
            #pragma unroll
            for (int r = 0; r < 3; ++r)
                acc1[c][r] = __builtin_amdgcn_mfma_f32_16x16x32_bf16(ef[c], af[r], acc1[c][r], 0, 0, 0);
    }

    // store D -> sD (bf16): lane holds D[i = i0+16r+l15][j = j0+16c+lk*4+q], 4 consecutive j
    // -> one ds_write_b64 per (c,r). Cols >=87 garbage; annihilated by W zero-pad.
    #pragma unroll
    for (int c = 0; c < 3; ++c) {
        const int jb = j0 + 16 * c + lk * 4;
        #pragma unroll
        for (int r = 0; r < 3; ++r) {
            const int i = i0 + 16 * r + l15;
            bf16x4 v;
            #pragma unroll
            for (int q = 0; q < 4; ++q) v[q] = f2bf(acc1[c][r][q]);
            *(bf16x4*)&sD[i * SP + jb] = v;
        }
    }

    // ---------------- GEMM2 x-half (independent of sD, runs before barrier) ----------------
    // Operand order mfma(wf, xf): acc2[wr][xc] -> reg dim = out col j, l15 = out row i.
    f32x4 acc2[3][3];
    #pragma unroll
    for (int wr = 0; wr < 3; ++wr)
        #pragma unroll
        for (int xc = 0; xc < 3; ++xc) acc2[wr][xc] = (f32x4){0.f, 0.f, 0.f, 0.f};

    #pragma unroll
    for (int ks = 0; ks < 3; ++ks) {
        const int k0 = ks * 32 + lk * 8;
        bf16x8 wf[3], xf[3];
        #pragma unroll
        for (int wr = 0; wr < 3; ++wr)
            wf[wr] = wload<WS>(wp, gW, 0, j0 + 16 * wr + l15, ja[wr], k0, ks == 2);
        #pragma unroll
        for (int xc = 0; xc < 3; ++xc) {
            float v[8];
            ld8tail(xb, ia[xc] * NN + k0, (ks == 2) && tailScalar, v);
            #pragma unroll
            for (int q = 0; q < 8; ++q) xf[xc][q] = f2bf(v[q]);
        }
        #pragma unroll
        for (int wr = 0; wr < 3; ++wr)
            #pragma unroll
            for (int xc = 0; xc < 3; ++xc)
                acc2[wr][xc] = __builtin_amdgcn_mfma_f32_16x16x32_bf16(wf[wr], xf[xc], acc2[wr][xc], 0, 0, 0);
    }

    __syncthreads();   // the ONLY barrier: sD writes -> sD reads

    // ---------------- GEMM2 D-half ----------------
    #pragma unroll
    for (int ks = 0; ks < 3; ++ks) {
        const int k0 = ks * 32 + lk * 8;
        bf16x8 wf[3], df[3];
        #pragma unroll
        for (int wr = 0; wr < 3; ++wr)
            wf[wr] = wload<WS>(wp, gW, 1, j0 + 16 * wr + l15, ja[wr], k0, ks == 2);
        #pragma unroll
        for (int xc = 0; xc < 3; ++xc)
            df[xc] = *(const bf16x8*)&sD[(i0 + 16 * xc + l15) * SP + k0];
        #pragma unroll
        for (int wr = 0; wr < 3; ++wr)
            #pragma unroll
            for (int xc = 0; xc < 3; ++xc)
                acc2[wr][xc] = __builtin_amdgcn_mfma_f32_16x16x32_bf16(wf[wr], df[xc], acc2[wr][xc], 0, 0, 0);
    }

    // ---------------- epilogue: lane stores 4 consecutive floats per tile ----------------
    float* __restrict__ ob = out + (size_t)b * NN2;
    #pragma unroll
    for (int wr = 0; wr < 3; ++wr) {
        const int jb = j0 + 16 * wr + lk * 4;
        float bj[4];
        if (jb + 3 < NN) {
            f32x4u t = *(const f32x4u*)(bias + jb);
            bj[0] = t.x; bj[1] = t.y; bj[2] = t.z; bj[3] = t.w;
        } else {
            #pragma unroll
            for (int q = 0; q < 4; ++q) bj[q] = (jb + q < NN) ? bias[jb + q] : 0.f;
        }
        #pragma unroll
        for (int xc = 0; xc < 3; ++xc) {
            const int i = i0 + 16 * xc + l15;
            if (i < NN) {
                if (jb + 3 < NN) {
                    f32x4u v;
                    v.x = acc2[wr][xc][0] + bj[0];
                    v.y = acc2[wr][xc][1] + bj[1];
                    v.z = acc2[wr][xc][2] + bj[2];
                    v.w = acc2[wr][xc][3] + bj[3];
                    *(f32x4u*)&ob[i * NN + jb] = v;
                } else {
                    #pragma unroll
                    for (int q = 0; q < 4; ++q)
                        if (jb + q < NN) ob[i * NN + jb + q] = acc2[wr][xc][q] + bj[q];
                }
            }
        }
    }
}

extern "C" void kernel_launch(void* const* d_in, const int* in_sizes, int n_in,
                              void* d_out, int out_size, void* d_ws, size_t ws_size,
                              hipStream_t stream)
{
    const float* x     = (const float*)d_in[0];
    const float* evals = (const float*)d_in[1];
    const float* evecs = (const float*)d_in[2];
    const float* dtime = (const float*)d_in[3];
    const float* W     = (const float*)d_in[4];
    const float* bias  = (const float*)d_in[5];
    float* out = (float*)d_out;

    const int B = in_sizes[1] / NN;   // evals is (B, 87)

    if (ws_size >= (size_t)WS_NEED) {
        const int prep_elems = 2 * PANEL + 2 * 7632 + 96;
        prep<<<(prep_elems + NT - 1) / NT, NT, 0, stream>>>(W, evals, evecs, x, B, (char*)d_ws);
        fused<true><<<dim3(B), dim3(NT), 0, stream>>>(x, evals, evecs, dtime, W, bias,
                                                      (const char*)d_ws, B, out);
    } else {
        fused<false><<<dim3(B), dim3(NT), 0, stream>>>(x, evals, evecs, dtime, W, bias,
                                                       nullptr, B, out);
    }
}

// Round 5
// 139.734 us; speedup vs baseline: 3.2325x; 3.2325x over previous
//
#include <hip/hip_runtime.h>
#include <math.h>

#define NN   87
#define NN2  (NN * NN)        // 7569
#define SP   104              // W-panel / sD row stride (bf16)
#define PANEL (96 * SP)       // 9984 shorts per panel
#define NT   256

// ws layout (bytes)
#define WS_W    0                       // 2 panels bf16 W     : 39936 B
#define WS_E    (2 * PANEL * 2)         // last-batch E padded : 7632 f
#define WS_X    (WS_E + 7632 * 4)       // last-batch x padded : 7632 f
#define WS_LAM  (WS_X + 7632 * 4)       // last-batch evals    : 96 f
#define WS_NEED (WS_LAM + 96 * 4)

typedef __attribute__((ext_vector_type(8))) short bf16x8;
typedef __attribute__((ext_vector_type(4))) short bf16x4;
typedef __attribute__((ext_vector_type(4))) float f32x4;
typedef float f32x4u __attribute__((ext_vector_type(4), aligned(4)));

__device__ __forceinline__ short f2bf(float f) {
    union { float f; unsigned u; } v; v.f = f;
    unsigned r = v.u + 0x7FFFu + ((v.u >> 16) & 1u);   // RNE
    return (short)(r >> 16);
}

__device__ __forceinline__ void ld8tail(const float* __restrict__ base, int off,
                                        bool scalarTail, float v[8]) {
    if (!scalarTail) {
        f32x4u a = *(const f32x4u*)(base + off);
        f32x4u b4 = *(const f32x4u*)(base + off + 4);
        v[0] = a.x; v[1] = a.y; v[2] = a.z; v[3] = a.w;
        v[4] = b4.x; v[5] = b4.y; v[6] = b4.z; v[7] = b4.w;
    } else {
        #pragma unroll
        for (int q = 0; q < 8; ++q) {
            int id = off + q;
            v[q] = base[(id < NN2) ? id : (NN2 - 1)];
        }
    }
}

__global__ void prep(const float* __restrict__ W, const float* __restrict__ evals,
                     const float* __restrict__ evecs, const float* __restrict__ x,
                     int B, char* __restrict__ ws)
{
    int idx = (int)blockIdx.x * NT + (int)threadIdx.x;
    short* wp = (short*)(ws + WS_W);
    float* ep = (float*)(ws + WS_E);
    float* xp = (float*)(ws + WS_X);
    float* lp = (float*)(ws + WS_LAM);

    if (idx < 2 * PANEL) {
        int p = idx / PANEL, rem = idx - p * PANEL;
        int r = rem / SP, c = rem - r * SP;
        short v = 0;
        if (r < NN && c < NN) v = f2bf(W[r * (2 * NN) + p * NN + c]);
        wp[idx] = v;
    }
    int i2 = idx - 2 * PANEL;
    if (i2 >= 0 && i2 < 7632) ep[i2] = (i2 < NN2) ? evecs[(size_t)(B - 1) * NN2 + i2] : 0.f;
    int i3 = i2 - 7632;
    if (i3 >= 0 && i3 < 7632) xp[i3] = (i3 < NN2) ? x[(size_t)(B - 1) * NN2 + i3] : 0.f;
    int i4 = i3 - 7632;
    if (i4 >= 0 && i4 < 96)   lp[i4] = (i4 < NN) ? evals[(size_t)(B - 1) * NN + i4] : 0.f;
}

template <bool WS>
__device__ __forceinline__ bf16x8 wload(const short* __restrict__ wp,
                                        const float* __restrict__ gW,
                                        int panel, int jrow, int jcl, int k0, bool tailKs)
{
    if constexpr (WS) {
        return *(const bf16x8*)&wp[panel * PANEL + jrow * SP + k0];
    } else {
        float v[8];
        if (!tailKs) {
            f32x4u a = *(const f32x4u*)(gW + jcl * (2 * NN) + panel * NN + k0);
            f32x4u b4 = *(const f32x4u*)(gW + jcl * (2 * NN) + panel * NN + k0 + 4);
            v[0] = a.x; v[1] = a.y; v[2] = a.z; v[3] = a.w;
            v[4] = b4.x; v[5] = b4.y; v[6] = b4.z; v[7] = b4.w;
        } else {
            #pragma unroll
            for (int q = 0; q < 8; ++q) {
                int k = k0 + q;
                v[q] = (k < NN) ? gW[jcl * (2 * NN) + panel * NN + k] : 0.f;
            }
        }
        bf16x8 o;
        #pragma unroll
        for (int q = 0; q < 8; ++q) o[q] = f2bf(v[q]);
        return o;
    }
}

template <bool WS>
__global__ __launch_bounds__(NT, 2)
void fused(const float* __restrict__ gx, const float* __restrict__ gevals,
           const float* __restrict__ gevecs, const float* __restrict__ dtime,
           const float* __restrict__ gW, const float* __restrict__ bias,
           const char* __restrict__ ws, int B, float* __restrict__ out)
{
    // union: sD (96x104 bf16 = 19968B) then sF (96x87 f32 packed = 33408B)
    __shared__ __align__(16) char uni[96 * NN * 4];
    short* const sD = (short*)uni;
    float* const sF = (float*)uni;

    const int b    = (int)blockIdx.x;
    const int tid  = (int)threadIdx.x;
    const int lane = tid & 63;
    const int wave = tid >> 6;
    const int l15  = lane & 15;
    const int lk   = lane >> 4;
    const int i0   = (wave >> 1) * 48;
    const int j0   = (wave & 1) * 48;
    const bool diag = (i0 == j0);

    const float* Eb   = gevecs + (size_t)b * NN2;
    const float* xb   = gx     + (size_t)b * NN2;
    const float* lamb = gevals + (size_t)b * NN;
    const short* wp = nullptr;
    if constexpr (WS) {
        wp = (const short*)(ws + WS_W);
        if (b == B - 1) {
            Eb   = (const float*)(ws + WS_E);
            xb   = (const float*)(ws + WS_X);
            lamb = (const float*)(ws + WS_LAM);
        }
    }
    const bool tailScalar = (!WS) && (b == B - 1);

    int ia[3], ja[3];
    float tr[3];
    #pragma unroll
    for (int r = 0; r < 3; ++r) {
        int i = i0 + 16 * r + l15;
        ia[r] = (i < NN) ? i : (NN - 1);
        tr[r] = fmaxf(dtime[ia[r]], 1e-8f);
        int j = j0 + 16 * r + l15;
        ja[r] = (j < NN) ? j : (NN - 1);
    }

    // hoisted lambda (masked for k>=87)
    float l8[3][8];
    #pragma unroll
    for (int ks = 0; ks < 3; ++ks) {
        const int k0 = ks * 32 + lk * 8;
        if (ks < 2 || !tailScalar) {
            f32x4u a  = *(const f32x4u*)(lamb + k0);
            f32x4u c4 = *(const f32x4u*)(lamb + k0 + 4);
            l8[ks][0] = a.x; l8[ks][1] = a.y; l8[ks][2] = a.z; l8[ks][3] = a.w;
            l8[ks][4] = c4.x; l8[ks][5] = c4.y; l8[ks][6] = c4.z; l8[ks][7] = c4.w;
        } else {
            #pragma unroll
            for (int q = 0; q < 8; ++q) { int k = k0 + q; l8[ks][q] = lamb[(k < NN) ? k : (NN - 1)]; }
        }
        if (ks == 2) {
            #pragma unroll
            for (int q = 0; q < 8; ++q)
                if (lk * 8 + q >= 23) l8[ks][q] = 3e38f;   // k >= 87 -> exp -> 0
        }
    }

    // ---------------- GEMM1: D = (E .* exp) @ E^T, swapped operands ----------------
    f32x4 acc1[3][3];
    #pragma unroll
    for (int c = 0; c < 3; ++c)
        #pragma unroll
        for (int r = 0; r < 3; ++r) acc1[c][r] = (f32x4){0.f, 0.f, 0.f, 0.f};

    #pragma unroll
    for (int ks = 0; ks < 3; ++ks) {
        const int k0 = ks * 32 + lk * 8;
        bf16x8 ef[3], af[3];
        float ve[3][8];
        #pragma unroll
        for (int c = 0; c < 3; ++c) {
            ld8tail(Eb, ja[c] * NN + k0, (ks == 2) && tailScalar, ve[c]);
            #pragma unroll
            for (int q = 0; q < 8; ++q) ef[c][q] = f2bf(ve[c][q]);
        }
        if (diag) {   // wave-uniform: i-rows == j-rows, reuse raw E values
            #pragma unroll
            for (int r = 0; r < 3; ++r)
                #pragma unroll
                for (int q = 0; q < 8; ++q)
                    af[r][q] = f2bf(ve[r][q] * __expf(-tr[r] * l8[ks][q]));
        } else {
            #pragma unroll
            for (int r = 0; r < 3; ++r) {
                float va[8];
                ld8tail(Eb, ia[r] * NN + k0, (ks == 2) && tailScalar, va);
                #pragma unroll
                for (int q = 0; q < 8; ++q)
                    af[r][q] = f2bf(va[q] * __expf(-tr[r] * l8[ks][q]));
            }
        }
        #pragma unroll
        for (int c = 0; c < 3; ++c)
            #pragma unroll
            for (int r = 0; r < 3; ++r)
                acc1[c][r] = __builtin_amdgcn_mfma_f32_16x16x32_bf16(ef[c], af[r], acc1[c][r], 0, 0, 0);
    }

    // store D -> sD: lane holds 4 consecutive j -> ds_write_b64
    #pragma unroll
    for (int c = 0; c < 3; ++c) {
        const int jb = j0 + 16 * c + lk * 4;
        #pragma unroll
        for (int r = 0; r < 3; ++r) {
            const int i = i0 + 16 * r + l15;
            bf16x4 v;
            #pragma unroll
            for (int q = 0; q < 4; ++q) v[q] = f2bf(acc1[c][r][q]);
            *(bf16x4*)&sD[i * SP + jb] = v;
        }
    }

    // hoist D-half W fragments: independent of sD, fly through x-half + barrier
    bf16x8 wfd[3][3];
    #pragma unroll
    for (int ks = 0; ks < 3; ++ks)
        #pragma unroll
        for (int wr = 0; wr < 3; ++wr)
            wfd[ks][wr] = wload<WS>(wp, gW, 1, j0 + 16 * wr + l15, ja[wr], ks * 32 + lk * 8, ks == 2);

    // ---------------- GEMM2 x-half ----------------
    f32x4 acc2[3][3];
    #pragma unroll
    for (int wr = 0; wr < 3; ++wr)
        #pragma unroll
        for (int xc = 0; xc < 3; ++xc) acc2[wr][xc] = (f32x4){0.f, 0.f, 0.f, 0.f};

    #pragma unroll
    for (int ks = 0; ks < 3; ++ks) {
        const int k0 = ks * 32 + lk * 8;
        bf16x8 wf[3], xf[3];
        #pragma unroll
        for (int wr = 0; wr < 3; ++wr)
            wf[wr] = wload<WS>(wp, gW, 0, j0 + 16 * wr + l15, ja[wr], k0, ks == 2);
        #pragma unroll
        for (int xc = 0; xc < 3; ++xc) {
            float v[8];
            ld8tail(xb, ia[xc] * NN + k0, (ks == 2) && tailScalar, v);
            #pragma unroll
            for (int q = 0; q < 8; ++q) xf[xc][q] = f2bf(v[q]);
        }
        #pragma unroll
        for (int wr = 0; wr < 3; ++wr)
            #pragma unroll
            for (int xc = 0; xc < 3; ++xc)
                acc2[wr][xc] = __builtin_amdgcn_mfma_f32_16x16x32_bf16(wf[wr], xf[xc], acc2[wr][xc], 0, 0, 0);
    }

    __syncthreads();   // barrier 1: sD ready

    // ---------------- GEMM2 D-half ----------------
    #pragma unroll
    for (int ks = 0; ks < 3; ++ks) {
        const int k0 = ks * 32 + lk * 8;
        bf16x8 df[3];
        #pragma unroll
        for (int xc = 0; xc < 3; ++xc)
            df[xc] = *(const bf16x8*)&sD[(i0 + 16 * xc + l15) * SP + k0];
        #pragma unroll
        for (int wr = 0; wr < 3; ++wr)
            #pragma unroll
            for (int xc = 0; xc < 3; ++xc)
                acc2[wr][xc] = __builtin_amdgcn_mfma_f32_16x16x32_bf16(wfd[ks][wr], df[xc], acc2[wr][xc], 0, 0, 0);
    }

    __syncthreads();   // barrier 2: all sD reads done before sF overwrite

    // ---------------- epilogue: pack out tile into sF (stride NN, packed) ----------------
    #pragma unroll
    for (int wr = 0; wr < 3; ++wr) {
        const int jb = j0 + 16 * wr + lk * 4;
        float bj[4];
        if (jb + 3 < NN) {
            f32x4u t = *(const f32x4u*)(bias + jb);
            bj[0] = t.x; bj[1] = t.y; bj[2] = t.z; bj[3] = t.w;
        } else {
            #pragma unroll
            for (int q = 0; q < 4; ++q) bj[q] = (jb + q < NN) ? bias[jb + q] : 0.f;
        }
        #pragma unroll
        for (int xc = 0; xc < 3; ++xc) {
            const int i = i0 + 16 * xc + l15;   // i<=95: rows >=87 land in sF pad rows, never copied
            #pragma unroll
            for (int q = 0; q < 4; ++q) {
                const int j = jb + q;
                if (j < NN) sF[i * NN + j] = acc2[wr][xc][q] + bj[q];
            }
        }
    }

    __syncthreads();   // barrier 3: sF complete

    // ---------------- copy-out: contiguous, alignment-fixed dwordx4 ----------------
    {
        float* __restrict__ gb = out + (size_t)b * NN2;
        const int s = (4 - ((b * NN2) & 3)) & 3;          // shift to 16B-align global
        if (tid < s) gb[tid] = sF[tid];
        const int C = (NN2 - s) >> 2;
        for (int m = tid; m < C; m += NT) {
            const int n = s + 4 * m;
            f32x4 v;
            v.x = sF[n]; v.y = sF[n + 1]; v.z = sF[n + 2]; v.w = sF[n + 3];
            *(f32x4*)(gb + n) = v;
        }
        const int tl = s + 4 * C;
        if (tid < NN2 - tl) gb[tl + tid] = sF[tl + tid];
    }
}

extern "C" void kernel_launch(void* const* d_in, const int* in_sizes, int n_in,
                              void* d_out, int out_size, void* d_ws, size_t ws_size,
                              hipStream_t stream)
{
    const float* x     = (const float*)d_in[0];
    const float* evals = (const float*)d_in[1];
    const float* evecs = (const float*)d_in[2];
    const float* dtime = (const float*)d_in[3];
    const float* W     = (const float*)d_in[4];
    const float* bias  = (const float*)d_in[5];
    float* out = (float*)d_out;

    const int B = in_sizes[1] / NN;   // evals is (B, 87)

    if (ws_size >= (size_t)WS_NEED) {
        const int prep_elems = 2 * PANEL + 2 * 7632 + 96;
        prep<<<(prep_elems + NT - 1) / NT, NT, 0, stream>>>(W, evals, evecs, x, B, (char*)d_ws);
        fused<true><<<dim3(B), dim3(NT), 0, stream>>>(x, evals, evecs, dtime, W, bias,
                                                      (const char*)d_ws, B, out);
    } else {
        fused<false><<<dim3(B), dim3(NT), 0, stream>>>(x, evals, evecs, dtime, W, bias,
                                                       nullptr, B, out);
    }
}